// Round 1
// baseline (529.572 us; speedup 1.0000x reference)
//
#include <hip/hip_runtime.h>
#include <cstdint>

#define N_NODES 4096
#define DM 64
#define K_DIM 8192   // S*N
#define M_DIM 2048   // B*DM

typedef unsigned short bf16u;
using bf16x8  = __attribute__((ext_vector_type(8))) short;
using floatx4 = __attribute__((ext_vector_type(4))) float;

__device__ inline bf16u f2bf(float f) {
  uint32_t u = __float_as_uint(f);
  u += 0x7FFF + ((u >> 16) & 1);   // round-to-nearest-even
  return (bf16u)(u >> 16);
}

#define GLOAD_LDS16(gp, lp)                                                     \
  __builtin_amdgcn_global_load_lds(                                             \
      reinterpret_cast<const __attribute__((address_space(1))) void*>(          \
          reinterpret_cast<uintptr_t>(gp)),                                     \
      reinterpret_cast<__attribute__((address_space(3))) void*>(                \
          (uint32_t)reinterpret_cast<uintptr_t>(lp)),                           \
      16, 0, 0)

// ---------------- kernel 1: adj f32 [S][N][N] -> BT bf16 [N][S*N] ----------------
// BT[w][s*N+v] = adj[s][w][v]   (k-major for the B^T GEMM; pure dtype convert)
__global__ __launch_bounds__(256) void k_adj2bt(const float* __restrict__ adj,
                                                bf16u* __restrict__ BT) {
  uint32_t idx = blockIdx.x * 256u + threadIdx.x;     // over S*N*(N/4) = 8,388,608
  uint32_t v4 = idx & 1023u;
  uint32_t w  = (idx >> 10) & 4095u;
  uint32_t s  = idx >> 22;
  float4 f = reinterpret_cast<const float4*>(adj)[idx];
  union { bf16u h[4]; uint2 u2; } pk;
  pk.h[0] = f2bf(f.x); pk.h[1] = f2bf(f.y); pk.h[2] = f2bf(f.z); pk.h[3] = f2bf(f.w);
  *reinterpret_cast<uint2*>(BT + ((size_t)w * K_DIM + s * N_NODES + v4 * 4)) = pk.u2;
}

// ---------------- kernel 2: A[(b*64+d)][s*4096+v] = sum_c Wmlp[d][s*65+c]*x_in[b][c][v]
__global__ __launch_bounds__(256) void k_mkA(const float* __restrict__ x,
                                             const float* __restrict__ h,
                                             const float* __restrict__ Wmlp,
                                             bf16u* __restrict__ A) {
  __shared__ __align__(16) float Ws[DM * 68];  // stride 68 keeps float4 rows 16B-aligned
  uint32_t base = blockIdx.x * 256u;
  uint32_t s = (base >> 12) & 1u;
  uint32_t b = base >> 13;
  uint32_t v = (base & 4095u) + threadIdx.x;
  for (uint32_t t = threadIdx.x; t < DM * 68; t += 256) {
    uint32_t d = t / 68u, c = t % 68u;
    Ws[t] = (c < 65u) ? Wmlp[d * 130u + s * 65u + c] : 0.f;
  }
  __syncthreads();

  float acc[DM];
#pragma unroll
  for (int d = 0; d < DM; ++d) acc[d] = 0.f;

  for (int c0 = 0; c0 < 64; c0 += 4) {           // channels 0..63
    float xv[4];
#pragma unroll
    for (int j = 0; j < 4; ++j) {
      int c = c0 + j;
      xv[j] = (c == 0) ? x[(size_t)b * N_NODES + v]
                       : h[((size_t)b * DM + (c - 1)) * N_NODES + v];
    }
#pragma unroll
    for (int d = 0; d < DM; ++d) {
      const float4 w4 = *reinterpret_cast<const float4*>(&Ws[d * 68 + c0]);
      acc[d] += w4.x * xv[0] + w4.y * xv[1] + w4.z * xv[2] + w4.w * xv[3];
    }
  }
  { // tail channel c=64 -> h row 63
    float xv = h[((size_t)b * DM + 63) * N_NODES + v];
#pragma unroll
    for (int d = 0; d < DM; ++d) acc[d] += Ws[d * 68 + 64] * xv;
  }
#pragma unroll
  for (int d = 0; d < DM; ++d)
    A[(size_t)(b * DM + d) * K_DIM + s * N_NODES + v] = f2bf(acc[d]);
}

// ---------------- kernel 3: C[m][n] = sum_k A[m][k]*BT[n][k]  (m97-style bf16 GEMM)
__global__ void k_gemm(const bf16u* __restrict__ A, const bf16u* __restrict__ BT,
                       float* __restrict__ C) {
  __shared__ __align__(16) bf16u As[128 * 32];
  __shared__ __align__(16) bf16u Bs[128 * 32];
  const int tid  = threadIdx.x;
  const int lane = tid & 63;
  const int wave = tid >> 6;
  const int wr = wave >> 1, wc = wave & 1;           // 2x2 wave grid, 64x64 each
  const int m0 = blockIdx.y * 128, n0 = blockIdx.x * 128;
  const int row_s = tid >> 2;                         // 0..63
  const int col_s = (tid & 3) * 8;                    // k offset, 8 bf16 = 16B

  const bf16u* Ag0 = A  + (size_t)(m0 + row_s)      * K_DIM + col_s;
  const bf16u* Ag1 = A  + (size_t)(m0 + 64 + row_s) * K_DIM + col_s;
  const bf16u* Bg0 = BT + (size_t)(n0 + row_s)      * K_DIM + col_s;
  const bf16u* Bg1 = BT + (size_t)(n0 + 64 + row_s) * K_DIM + col_s;

  bf16u* AsW0 = As + wave * 512;          // wave-uniform LDS bases (lane*16B appended by HW)
  bf16u* AsW1 = As + 2048 + wave * 512;
  bf16u* BsW0 = Bs + wave * 512;
  bf16u* BsW1 = Bs + 2048 + wave * 512;

  floatx4 acc[4][4];
#pragma unroll
  for (int i = 0; i < 4; ++i)
#pragma unroll
    for (int j = 0; j < 4; ++j) acc[i][j] = (floatx4){0.f, 0.f, 0.f, 0.f};

  const int fRow = lane & 15;   // A: m, B: n
  const int fQ   = lane >> 4;   // quad -> k = fQ*8 + j

  for (int k0 = 0; k0 < K_DIM; k0 += 32) {
    GLOAD_LDS16(Ag0 + k0, AsW0);
    GLOAD_LDS16(Ag1 + k0, AsW1);
    GLOAD_LDS16(Bg0 + k0, BsW0);
    GLOAD_LDS16(Bg1 + k0, BsW1);
    __syncthreads();

    bf16x8 af[4], bfr[4];
#pragma unroll
    for (int i = 0; i < 4; ++i)
      af[i] = *reinterpret_cast<const bf16x8*>(&As[(wr * 64 + i * 16 + fRow) * 32 + fQ * 8]);
#pragma unroll
    for (int j = 0; j < 4; ++j)
      bfr[j] = *reinterpret_cast<const bf16x8*>(&Bs[(wc * 64 + j * 16 + fRow) * 32 + fQ * 8]);
#pragma unroll
    for (int i = 0; i < 4; ++i)
#pragma unroll
      for (int j = 0; j < 4; ++j)
        acc[i][j] = __builtin_amdgcn_mfma_f32_16x16x32_bf16(af[i], bfr[j], acc[i][j], 0, 0, 0);
    __syncthreads();
  }

  // verified C/D mapping: col = lane&15, row = (lane>>4)*4 + reg
  const int cr = (lane >> 4) * 4;
  const int cc = lane & 15;
#pragma unroll
  for (int i = 0; i < 4; ++i)
#pragma unroll
    for (int j = 0; j < 4; ++j) {
      float* Cp = C + (size_t)(m0 + wr * 64 + i * 16 + cr) * N_NODES
                    + (n0 + wc * 64 + j * 16 + cc);
#pragma unroll
      for (int r = 0; r < 4; ++r) Cp[(size_t)r * N_NODES] = acc[i][j][r];
    }
}

// ---------------- kernel 4: epilogue: bias, W_lin, PReLU, concat h, W_read
__global__ __launch_bounds__(256) void k_epilogue(
    const float* __restrict__ Cpre, const float* __restrict__ h,
    const float* __restrict__ bmlp, const float* __restrict__ Wlin,
    const float* __restrict__ blin, const float* __restrict__ Wread,
    const float* __restrict__ bread, const float* __restrict__ pa,
    float* __restrict__ out0, float* __restrict__ out1) {
  __shared__ __align__(16) float sW[DM * 128];   // 32 KB
  __shared__ float sbm[DM], sbl[DM], sWr[128];
  for (uint32_t t = threadIdx.x; t < DM * 128; t += 256) sW[t] = Wlin[t];
  if (threadIdx.x < DM) { sbm[threadIdx.x] = bmlp[threadIdx.x]; sbl[threadIdx.x] = blin[threadIdx.x]; }
  if (threadIdx.x < 128) sWr[threadIdx.x] = Wread[threadIdx.x];
  __syncthreads();

  uint32_t idx = blockIdx.x * 256u + threadIdx.x;  // B*N = 131072
  uint32_t n = idx & 4095u, b = idx >> 12;

  float acc[DM];
#pragma unroll
  for (int d = 0; d < DM; ++d) acc[d] = sbl[d];

  for (int c0 = 0; c0 < 64; c0 += 4) {             // first half: graph-conv out + b_mlp
    float in4[4];
#pragma unroll
    for (int j = 0; j < 4; ++j)
      in4[j] = Cpre[((size_t)b * DM + (c0 + j)) * N_NODES + n] + sbm[c0 + j];
#pragma unroll
    for (int d = 0; d < DM; ++d) {
      float4 w4 = *reinterpret_cast<const float4*>(&sW[d * 128 + c0]);
      acc[d] += w4.x * in4[0] + w4.y * in4[1] + w4.z * in4[2] + w4.w * in4[3];
    }
  }
  for (int c0 = 0; c0 < 64; c0 += 4) {             // second half: h
    float in4[4];
#pragma unroll
    for (int j = 0; j < 4; ++j)
      in4[j] = h[((size_t)b * DM + (c0 + j)) * N_NODES + n];
#pragma unroll
    for (int d = 0; d < DM; ++d) {
      float4 w4 = *reinterpret_cast<const float4*>(&sW[d * 128 + 64 + c0]);
      acc[d] += w4.x * in4[0] + w4.y * in4[1] + w4.z * in4[2] + w4.w * in4[3];
    }
  }

  const float a = pa[0];
  float r = bread[0];
  float* o1b = out1 + (size_t)b * 128 * N_NODES + n;
#pragma unroll
  for (int d = 0; d < DM; ++d) {
    float o2 = acc[d] >= 0.f ? acc[d] : a * acc[d];   // PReLU
    o1b[(size_t)d * N_NODES] = o2;
    r += sWr[d] * o2;
  }
#pragma unroll
  for (int j = 0; j < DM; ++j) {
    float hv = h[((size_t)b * DM + j) * N_NODES + n];
    o1b[(size_t)(64 + j) * N_NODES] = hv;
    r += sWr[64 + j] * hv;
  }
  out0[idx] = r;
}

extern "C" void kernel_launch(void* const* d_in, const int* in_sizes, int n_in,
                              void* d_out, int out_size, void* d_ws, size_t ws_size,
                              hipStream_t stream) {
  const float* x     = (const float*)d_in[0];
  const float* h     = (const float*)d_in[1];
  const float* adj   = (const float*)d_in[2];
  const float* Wmlp  = (const float*)d_in[3];
  const float* bmlp  = (const float*)d_in[4];
  const float* Wlin  = (const float*)d_in[5];
  const float* blin  = (const float*)d_in[6];
  const float* Wread = (const float*)d_in[7];
  const float* bread = (const float*)d_in[8];
  const float* pa    = (const float*)d_in[9];

  char* ws = (char*)d_ws;
  bf16u* Abuf  = (bf16u*)ws;                     // 2048*8192*2  = 32 MiB
  bf16u* BTbuf = (bf16u*)(ws + 33554432ull);     // 4096*8192*2  = 64 MiB
  float* Cbuf  = (float*)(ws + 100663296ull);    // 2048*4096*4  = 32 MiB
  float* out0 = (float*)d_out;                   // [32,1,4096]
  float* out1 = out0 + 131072;                   // [32,128,4096]

  hipLaunchKernelGGL(k_adj2bt,   dim3(32768),  dim3(256), 0, stream, adj, BTbuf);
  hipLaunchKernelGGL(k_mkA,      dim3(1024),   dim3(256), 0, stream, x, h, Wmlp, Abuf);
  hipLaunchKernelGGL(k_gemm,     dim3(32, 16), dim3(256), 0, stream, Abuf, BTbuf, Cbuf);
  hipLaunchKernelGGL(k_epilogue, dim3(512),    dim3(256), 0, stream, Cbuf, h, bmlp,
                     Wlin, blin, Wread, bread, pa, out0, out1);
}

// Round 2
// 500.563 us; speedup vs baseline: 1.0580x; 1.0580x over previous
//
#include <hip/hip_runtime.h>
#include <cstdint>

#define N_NODES 4096
#define DM 64
#define K_DIM 8192   // S*N
#define M_DIM 2048   // B*DM

typedef unsigned short bf16u;
using bf16x8  = __attribute__((ext_vector_type(8))) short;
using floatx4 = __attribute__((ext_vector_type(4))) float;

__device__ inline bf16u f2bf(float f) {
  uint32_t u = __float_as_uint(f);
  u += 0x7FFF + ((u >> 16) & 1);   // round-to-nearest-even
  return (bf16u)(u >> 16);
}

#define GLOAD_LDS16(gp, lp)                                                     \
  __builtin_amdgcn_global_load_lds(                                             \
      reinterpret_cast<const __attribute__((address_space(1))) void*>(          \
          reinterpret_cast<uintptr_t>(gp)),                                     \
      reinterpret_cast<__attribute__((address_space(3))) void*>(                \
          (uint32_t)reinterpret_cast<uintptr_t>(lp)),                           \
      16, 0, 0)

// ---------------- kernel 1: adj f32 [S][N][N] -> BT bf16 [N][S*N] ----------------
// 8 elems/thread: two float4 loads -> one 16B store
__global__ __launch_bounds__(256) void k_adj2bt(const float* __restrict__ adj,
                                                bf16u* __restrict__ BT) {
  uint32_t idx = blockIdx.x * 256u + threadIdx.x;     // over S*N*(N/8) = 4,194,304
  uint32_t v8 = idx & 511u;
  uint32_t w  = (idx >> 9) & 4095u;
  uint32_t s  = idx >> 21;
  const float4* src = reinterpret_cast<const float4*>(adj) + (size_t)idx * 2;
  float4 f0 = src[0], f1 = src[1];
  union { bf16u h[8]; uint4 u4; } pk;
  pk.h[0] = f2bf(f0.x); pk.h[1] = f2bf(f0.y); pk.h[2] = f2bf(f0.z); pk.h[3] = f2bf(f0.w);
  pk.h[4] = f2bf(f1.x); pk.h[5] = f2bf(f1.y); pk.h[6] = f2bf(f1.z); pk.h[7] = f2bf(f1.w);
  *reinterpret_cast<uint4*>(BT + ((size_t)w * K_DIM + s * N_NODES + v8 * 8)) = pk.u4;
}

// ---------------- kernel 2: A[(b*64+d)][s*4096+v] = sum_c Wmlp[d][s*65+c]*x_in[b][c][v]
// tile: thread owns 4 consecutive v x 16 d  (acc[16][4]) -> LDS weight reads /4
__global__ __launch_bounds__(256) void k_mkA(const float* __restrict__ x,
                                             const float* __restrict__ h,
                                             const float* __restrict__ Wmlp,
                                             bf16u* __restrict__ A) {
  __shared__ __align__(16) float Ws[DM * 68];  // stride 68: 272B rows, 16B-aligned float4
  uint32_t bi = blockIdx.x;                    // 32 b x 2 s x 16 v0 = 1024 blocks
  uint32_t v0 = (bi & 15u) * 256u;
  uint32_t s  = (bi >> 4) & 1u;
  uint32_t b  = bi >> 5;
  for (uint32_t t = threadIdx.x; t < DM * 68; t += 256) {
    uint32_t d = t / 68u, c = t % 68u;
    Ws[t] = (c < 65u) ? Wmlp[d * 130u + s * 65u + c] : 0.f;
  }
  __syncthreads();

  const uint32_t tv = threadIdx.x & 63u;
  const uint32_t td = threadIdx.x >> 6;        // wave-uniform -> LDS broadcast
  const uint32_t v  = v0 + tv * 4u;

  float acc[16][4];
#pragma unroll
  for (int d = 0; d < 16; ++d)
#pragma unroll
    for (int k = 0; k < 4; ++k) acc[d][k] = 0.f;

  for (int c0 = 0; c0 < 64; c0 += 4) {
    float4 in4[4];
#pragma unroll
    for (int j = 0; j < 4; ++j) {
      int c = c0 + j;
      const float* src = (c == 0) ? (x + (size_t)b * N_NODES + v)
                                  : (h + ((size_t)b * DM + (c - 1)) * N_NODES + v);
      in4[j] = *reinterpret_cast<const float4*>(src);
    }
#pragma unroll
    for (int d = 0; d < 16; ++d) {
      const float4 w4 = *reinterpret_cast<const float4*>(&Ws[(td * 16 + d) * 68 + c0]);
      acc[d][0] += w4.x * in4[0].x + w4.y * in4[1].x + w4.z * in4[2].x + w4.w * in4[3].x;
      acc[d][1] += w4.x * in4[0].y + w4.y * in4[1].y + w4.z * in4[2].y + w4.w * in4[3].y;
      acc[d][2] += w4.x * in4[0].z + w4.y * in4[1].z + w4.z * in4[2].z + w4.w * in4[3].z;
      acc[d][3] += w4.x * in4[0].w + w4.y * in4[1].w + w4.z * in4[2].w + w4.w * in4[3].w;
    }
  }
  { // tail channel c=64 -> h row 63
    float4 in4 = *reinterpret_cast<const float4*>(h + ((size_t)b * DM + 63) * N_NODES + v);
#pragma unroll
    for (int d = 0; d < 16; ++d) {
      float w = Ws[(td * 16 + d) * 68 + 64];
      acc[d][0] += w * in4.x; acc[d][1] += w * in4.y;
      acc[d][2] += w * in4.z; acc[d][3] += w * in4.w;
    }
  }
#pragma unroll
  for (int d = 0; d < 16; ++d) {
    union { bf16u h4[4]; uint2 u2; } pk;
#pragma unroll
    for (int k = 0; k < 4; ++k) pk.h4[k] = f2bf(acc[d][k]);
    *reinterpret_cast<uint2*>(A + (size_t)(b * DM + td * 16 + d) * K_DIM + s * N_NODES + v) = pk.u2;
  }
}

// ---------------- kernel 3: C[m][n] = sum_k A[m][k]*BT[n][k]  (m97-style bf16 GEMM)
__global__ void k_gemm(const bf16u* __restrict__ A, const bf16u* __restrict__ BT,
                       float* __restrict__ C) {
  __shared__ __align__(16) bf16u As[128 * 32];
  __shared__ __align__(16) bf16u Bs[128 * 32];
  const int tid  = threadIdx.x;
  const int lane = tid & 63;
  const int wave = tid >> 6;
  const int wr = wave >> 1, wc = wave & 1;           // 2x2 wave grid, 64x64 each
  const int m0 = blockIdx.y * 128, n0 = blockIdx.x * 128;
  const int row_s = tid >> 2;                         // 0..63
  const int col_s = (tid & 3) * 8;                    // k offset, 8 bf16 = 16B

  const bf16u* Ag0 = A  + (size_t)(m0 + row_s)      * K_DIM + col_s;
  const bf16u* Ag1 = A  + (size_t)(m0 + 64 + row_s) * K_DIM + col_s;
  const bf16u* Bg0 = BT + (size_t)(n0 + row_s)      * K_DIM + col_s;
  const bf16u* Bg1 = BT + (size_t)(n0 + 64 + row_s) * K_DIM + col_s;

  bf16u* AsW0 = As + wave * 512;          // wave-uniform LDS bases (lane*16B appended by HW)
  bf16u* AsW1 = As + 2048 + wave * 512;
  bf16u* BsW0 = Bs + wave * 512;
  bf16u* BsW1 = Bs + 2048 + wave * 512;

  floatx4 acc[4][4];
#pragma unroll
  for (int i = 0; i < 4; ++i)
#pragma unroll
    for (int j = 0; j < 4; ++j) acc[i][j] = (floatx4){0.f, 0.f, 0.f, 0.f};

  const int fRow = lane & 15;   // A: m, B: n
  const int fQ   = lane >> 4;   // quad -> k = fQ*8 + j

  for (int k0 = 0; k0 < K_DIM; k0 += 32) {
    GLOAD_LDS16(Ag0 + k0, AsW0);
    GLOAD_LDS16(Ag1 + k0, AsW1);
    GLOAD_LDS16(Bg0 + k0, BsW0);
    GLOAD_LDS16(Bg1 + k0, BsW1);
    __syncthreads();

    bf16x8 af[4], bfr[4];
#pragma unroll
    for (int i = 0; i < 4; ++i)
      af[i] = *reinterpret_cast<const bf16x8*>(&As[(wr * 64 + i * 16 + fRow) * 32 + fQ * 8]);
#pragma unroll
    for (int j = 0; j < 4; ++j)
      bfr[j] = *reinterpret_cast<const bf16x8*>(&Bs[(wc * 64 + j * 16 + fRow) * 32 + fQ * 8]);
#pragma unroll
    for (int i = 0; i < 4; ++i)
#pragma unroll
      for (int j = 0; j < 4; ++j)
        acc[i][j] = __builtin_amdgcn_mfma_f32_16x16x32_bf16(af[i], bfr[j], acc[i][j], 0, 0, 0);
    __syncthreads();
  }

  // verified C/D mapping: col = lane&15, row = (lane>>4)*4 + reg
  const int cr = (lane >> 4) * 4;
  const int cc = lane & 15;
#pragma unroll
  for (int i = 0; i < 4; ++i)
#pragma unroll
    for (int j = 0; j < 4; ++j) {
      float* Cp = C + (size_t)(m0 + wr * 64 + i * 16 + cr) * N_NODES
                    + (n0 + wc * 64 + j * 16 + cc);
#pragma unroll
      for (int r = 0; r < 4; ++r) Cp[(size_t)r * N_NODES] = acc[i][j][r];
    }
}

// ---------------- kernel 4: epilogue: bias, W_lin, PReLU, concat h, W_read
// tile: thread owns 4 consecutive n x 16 d'  (acc[16][4]) -> LDS weight reads /4
__global__ __launch_bounds__(256) void k_epilogue(
    const float* __restrict__ Cpre, const float* __restrict__ h,
    const float* __restrict__ bmlp, const float* __restrict__ Wlin,
    const float* __restrict__ blin, const float* __restrict__ Wread,
    const float* __restrict__ bread, const float* __restrict__ pa,
    float* __restrict__ out0, float* __restrict__ out1) {
  __shared__ __align__(16) float sW[DM * 132];   // stride 132: rows 528B, 16B-aligned
  __shared__ float sbm[DM], sbl[DM], sWr[128];
  __shared__ float psum[3 * 256];
  for (uint32_t t = threadIdx.x; t < DM * 128; t += 256) {
    uint32_t d = t >> 7, c = t & 127u;
    sW[d * 132 + c] = Wlin[t];
  }
  if (threadIdx.x < DM) { sbm[threadIdx.x] = bmlp[threadIdx.x]; sbl[threadIdx.x] = blin[threadIdx.x]; }
  if (threadIdx.x < 128) sWr[threadIdx.x] = Wread[threadIdx.x];
  __syncthreads();

  uint32_t bi = blockIdx.x;                  // 32 b x 16 n0 = 512 blocks
  uint32_t n0 = (bi & 15u) * 256u;
  uint32_t b  = bi >> 4;
  const uint32_t tv = threadIdx.x & 63u;
  const uint32_t td = threadIdx.x >> 6;      // wave-uniform
  const uint32_t n  = n0 + tv * 4u;

  float acc[16][4];
#pragma unroll
  for (int d = 0; d < 16; ++d) {
    float bl = sbl[td * 16 + d];
#pragma unroll
    for (int k = 0; k < 4; ++k) acc[d][k] = bl;
  }

  // first half: channels 0..63 = graph-conv out (Cpre + bmlp)
  for (int c0 = 0; c0 < 64; c0 += 4) {
    float4 in4[4];
#pragma unroll
    for (int j = 0; j < 4; ++j) {
      float4 v = *reinterpret_cast<const float4*>(Cpre + ((size_t)b * DM + (c0 + j)) * N_NODES + n);
      float bm = sbm[c0 + j];
      v.x += bm; v.y += bm; v.z += bm; v.w += bm;
      in4[j] = v;
    }
#pragma unroll
    for (int d = 0; d < 16; ++d) {
      const float4 w4 = *reinterpret_cast<const float4*>(&sW[(td * 16 + d) * 132 + c0]);
      acc[d][0] += w4.x * in4[0].x + w4.y * in4[1].x + w4.z * in4[2].x + w4.w * in4[3].x;
      acc[d][1] += w4.x * in4[0].y + w4.y * in4[1].y + w4.z * in4[2].y + w4.w * in4[3].y;
      acc[d][2] += w4.x * in4[0].z + w4.y * in4[1].z + w4.z * in4[2].z + w4.w * in4[3].z;
      acc[d][3] += w4.x * in4[0].w + w4.y * in4[1].w + w4.z * in4[2].w + w4.w * in4[3].w;
    }
  }
  // second half: channels 64..127 = h
  for (int c0 = 0; c0 < 64; c0 += 4) {
    float4 in4[4];
#pragma unroll
    for (int j = 0; j < 4; ++j)
      in4[j] = *reinterpret_cast<const float4*>(h + ((size_t)b * DM + (c0 + j)) * N_NODES + n);
#pragma unroll
    for (int d = 0; d < 16; ++d) {
      const float4 w4 = *reinterpret_cast<const float4*>(&sW[(td * 16 + d) * 132 + 64 + c0]);
      acc[d][0] += w4.x * in4[0].x + w4.y * in4[1].x + w4.z * in4[2].x + w4.w * in4[3].x;
      acc[d][1] += w4.x * in4[0].y + w4.y * in4[1].y + w4.z * in4[2].y + w4.w * in4[3].y;
      acc[d][2] += w4.x * in4[0].z + w4.y * in4[1].z + w4.z * in4[2].z + w4.w * in4[3].z;
      acc[d][3] += w4.x * in4[0].w + w4.y * in4[1].w + w4.z * in4[2].w + w4.w * in4[3].w;
    }
  }

  const float a = pa[0];
  float r[4] = {0.f, 0.f, 0.f, 0.f};
  float* o1b = out1 + (size_t)b * 128 * N_NODES + n;
#pragma unroll
  for (int d = 0; d < 16; ++d) {
    float4 o2;
    o2.x = acc[d][0] >= 0.f ? acc[d][0] : a * acc[d][0];
    o2.y = acc[d][1] >= 0.f ? acc[d][1] : a * acc[d][1];
    o2.z = acc[d][2] >= 0.f ? acc[d][2] : a * acc[d][2];
    o2.w = acc[d][3] >= 0.f ? acc[d][3] : a * acc[d][3];
    *reinterpret_cast<float4*>(o1b + (size_t)(td * 16 + d) * N_NODES) = o2;
    float wr = sWr[td * 16 + d];
    r[0] += wr * o2.x; r[1] += wr * o2.y; r[2] += wr * o2.z; r[3] += wr * o2.w;
  }
  // h rows td*16..td*16+15 -> out1 rows 64+..., plus Wread partial
#pragma unroll
  for (int d = 0; d < 16; ++d) {
    float4 hv = *reinterpret_cast<const float4*>(h + ((size_t)b * DM + td * 16 + d) * N_NODES + n);
    *reinterpret_cast<float4*>(o1b + (size_t)(64 + td * 16 + d) * N_NODES) = hv;
    float wr = sWr[64 + td * 16 + d];
    r[0] += wr * hv.x; r[1] += wr * hv.y; r[2] += wr * hv.z; r[3] += wr * hv.w;
  }
  if (td > 0) {
#pragma unroll
    for (int k = 0; k < 4; ++k) psum[(td - 1) * 256 + tv * 4 + k] = r[k];
  }
  __syncthreads();
  if (td == 0) {
    float br = bread[0];
#pragma unroll
    for (int k = 0; k < 4; ++k)
      r[k] += br + psum[tv * 4 + k] + psum[256 + tv * 4 + k] + psum[512 + tv * 4 + k];
    float4 o0; o0.x = r[0]; o0.y = r[1]; o0.z = r[2]; o0.w = r[3];
    *reinterpret_cast<float4*>(out0 + (size_t)b * N_NODES + n) = o0;
  }
}

extern "C" void kernel_launch(void* const* d_in, const int* in_sizes, int n_in,
                              void* d_out, int out_size, void* d_ws, size_t ws_size,
                              hipStream_t stream) {
  const float* x     = (const float*)d_in[0];
  const float* h     = (const float*)d_in[1];
  const float* adj   = (const float*)d_in[2];
  const float* Wmlp  = (const float*)d_in[3];
  const float* bmlp  = (const float*)d_in[4];
  const float* Wlin  = (const float*)d_in[5];
  const float* blin  = (const float*)d_in[6];
  const float* Wread = (const float*)d_in[7];
  const float* bread = (const float*)d_in[8];
  const float* pa    = (const float*)d_in[9];

  char* ws = (char*)d_ws;
  bf16u* Abuf  = (bf16u*)ws;                     // 2048*8192*2  = 32 MiB
  bf16u* BTbuf = (bf16u*)(ws + 33554432ull);     // 4096*8192*2  = 64 MiB
  float* Cbuf  = (float*)(ws + 100663296ull);    // 2048*4096*4  = 32 MiB
  float* out0 = (float*)d_out;                   // [32,1,4096]
  float* out1 = out0 + 131072;                   // [32,128,4096]

  hipLaunchKernelGGL(k_adj2bt,   dim3(16384),  dim3(256), 0, stream, adj, BTbuf);
  hipLaunchKernelGGL(k_mkA,      dim3(1024),   dim3(256), 0, stream, x, h, Wmlp, Abuf);
  hipLaunchKernelGGL(k_gemm,     dim3(32, 16), dim3(256), 0, stream, Abuf, BTbuf, Cbuf);
  hipLaunchKernelGGL(k_epilogue, dim3(512),    dim3(256), 0, stream, Cbuf, h, bmlp,
                     Wlin, blin, Wread, bread, pa, out0, out1);
}

// Round 3
// 422.866 us; speedup vs baseline: 1.2523x; 1.1837x over previous
//
#include <hip/hip_runtime.h>
#include <cstdint>

#define N_NODES 4096
#define DM 64
#define K_DIM 8192   // S*N
#define M_DIM 2048   // B*DM

typedef uint8_t u8;
using i32x8   = __attribute__((ext_vector_type(8))) int;
using floatx4 = __attribute__((ext_vector_type(4))) float;

#define GLOAD_LDS16(gp, lp)                                                     \
  __builtin_amdgcn_global_load_lds(                                             \
      reinterpret_cast<const __attribute__((address_space(1))) void*>(          \
          reinterpret_cast<uintptr_t>(gp)),                                     \
      reinterpret_cast<__attribute__((address_space(3))) void*>(                \
          (uint32_t)reinterpret_cast<uintptr_t>(lp)),                           \
      16, 0, 0)

// pack 4 floats -> 4 fp8(e4m3) bytes in one int, byte i = f[i]
__device__ inline int pk_fp8x4(float f0, float f1, float f2, float f3) {
  int r = __builtin_amdgcn_cvt_pk_fp8_f32(f0, f1, 0, false);   // bytes 0,1
  r     = __builtin_amdgcn_cvt_pk_fp8_f32(f2, f3, r, true);    // bytes 2,3
  return r;
}

// ---------------- kernel 1 (fused prep):
// blocks [0,16384):  BT8[w][s*N+v] = fp8( adj[s][w][v] * 4096 )   (value in U(0,1))
// blocks [16384,17408): A8[(b*64+d)][s*N+v] = fp8( sum_c Wmlp[d][s*65+c]*x_in[b][c][v] )
__global__ __launch_bounds__(256) void k_prep(const float* __restrict__ adj,
                                              u8* __restrict__ BT8,
                                              const float* __restrict__ x,
                                              const float* __restrict__ h,
                                              const float* __restrict__ Wmlp,
                                              u8* __restrict__ A8) {
  __shared__ __align__(16) float Ws[DM * 68];
  uint32_t bi = blockIdx.x;
  if (bi < 16384u) {
    // ---- adj -> fp8 BT, 8 elems/thread ----
    uint32_t idx = bi * 256u + threadIdx.x;           // over S*N*(N/8) = 4,194,304
    uint32_t v8 = idx & 511u;
    uint32_t w  = (idx >> 9) & 4095u;
    uint32_t s  = idx >> 21;
    const float4* src = reinterpret_cast<const float4*>(adj) + (size_t)idx * 2;
    float4 f0 = src[0], f1 = src[1];
    uint2 pk;
    pk.x = (uint32_t)pk_fp8x4(f0.x * 4096.f, f0.y * 4096.f, f0.z * 4096.f, f0.w * 4096.f);
    pk.y = (uint32_t)pk_fp8x4(f1.x * 4096.f, f1.y * 4096.f, f1.z * 4096.f, f1.w * 4096.f);
    *reinterpret_cast<uint2*>(BT8 + ((size_t)w * K_DIM + s * N_NODES + v8 * 8)) = pk;
    return;
  }
  // ---- build A (folded W_mlp), thread owns 4 v x 16 d ----
  uint32_t b2 = bi - 16384u;                          // 32 b x 2 s x 16 v0 = 1024
  uint32_t v0 = (b2 & 15u) * 256u;
  uint32_t s  = (b2 >> 4) & 1u;
  uint32_t b  = b2 >> 5;
  for (uint32_t t = threadIdx.x; t < DM * 68; t += 256) {
    uint32_t d = t / 68u, c = t % 68u;
    Ws[t] = (c < 65u) ? Wmlp[d * 130u + s * 65u + c] : 0.f;
  }
  __syncthreads();

  const uint32_t tv = threadIdx.x & 63u;
  const uint32_t td = threadIdx.x >> 6;               // wave-uniform -> LDS broadcast
  const uint32_t v  = v0 + tv * 4u;

  float acc[16][4];
#pragma unroll
  for (int d = 0; d < 16; ++d)
#pragma unroll
    for (int k = 0; k < 4; ++k) acc[d][k] = 0.f;

  for (int c0 = 0; c0 < 64; c0 += 4) {
    float4 in4[4];
#pragma unroll
    for (int j = 0; j < 4; ++j) {
      int c = c0 + j;
      const float* src = (c == 0) ? (x + (size_t)b * N_NODES + v)
                                  : (h + ((size_t)b * DM + (c - 1)) * N_NODES + v);
      in4[j] = *reinterpret_cast<const float4*>(src);
    }
#pragma unroll
    for (int d = 0; d < 16; ++d) {
      const float4 w4 = *reinterpret_cast<const float4*>(&Ws[(td * 16 + d) * 68 + c0]);
      acc[d][0] += w4.x * in4[0].x + w4.y * in4[1].x + w4.z * in4[2].x + w4.w * in4[3].x;
      acc[d][1] += w4.x * in4[0].y + w4.y * in4[1].y + w4.z * in4[2].y + w4.w * in4[3].y;
      acc[d][2] += w4.x * in4[0].z + w4.y * in4[1].z + w4.z * in4[2].z + w4.w * in4[3].z;
      acc[d][3] += w4.x * in4[0].w + w4.y * in4[1].w + w4.z * in4[2].w + w4.w * in4[3].w;
    }
  }
  { // tail channel c=64 -> h row 63
    float4 in4 = *reinterpret_cast<const float4*>(h + ((size_t)b * DM + 63) * N_NODES + v);
#pragma unroll
    for (int d = 0; d < 16; ++d) {
      float w = Ws[(td * 16 + d) * 68 + 64];
      acc[d][0] += w * in4.x; acc[d][1] += w * in4.y;
      acc[d][2] += w * in4.z; acc[d][3] += w * in4.w;
    }
  }
#pragma unroll
  for (int d = 0; d < 16; ++d) {
    int p = pk_fp8x4(acc[d][0], acc[d][1], acc[d][2], acc[d][3]);
    *reinterpret_cast<int*>(A8 + (size_t)(b * DM + td * 16 + d) * K_DIM + s * N_NODES + v) = p;
  }
}

// ---------------- kernel 2: C_z[m][n] = sum_{k in half z} A8[m][k]*BT8[n][k]
// MX-fp8 MFMA 16x16x128, constant scale 1.0; 128x128 tile, BK=128, split-K=2.
// LDS layout [quad][row][32B]: lane's 32B fragment contiguous; 4-way bank alias.
__global__ void k_gemm(const u8* __restrict__ A, const u8* __restrict__ BT,
                       float* __restrict__ C) {
  __shared__ __align__(32) u8 As[4][128][32];   // 16 KB
  __shared__ __align__(32) u8 Bs[4][128][32];   // 16 KB
  const int tid  = threadIdx.x;
  const int lane = tid & 63;
  const int wave = tid >> 6;
  const int wr = wave >> 1, wc = wave & 1;      // 2x2 wave grid, 64x64 each
  const int m0 = blockIdx.y * 128, n0 = blockIdx.x * 128;
  const size_t kb = (size_t)blockIdx.z * 4096;

  // staging: instr (wave, q) covers rows [wave*32, wave*32+32) of quad-chunk q.
  // lane l -> row wave*32 + (l>>1), byte offset (l&1)*16  (matches base + l*16)
  const int srow = lane >> 1;
  const int shalf = (lane & 1) * 16;
  const u8* Ag = A  + (size_t)(m0 + wave * 32 + srow) * K_DIM + kb + shalf;
  const u8* Bg = BT + (size_t)(n0 + wave * 32 + srow) * K_DIM + kb + shalf;
  u8* AsB[4]; u8* BsB[4];
#pragma unroll
  for (int q = 0; q < 4; ++q) { AsB[q] = &As[q][wave * 32][0]; BsB[q] = &Bs[q][wave * 32][0]; }

  floatx4 acc[4][4];
#pragma unroll
  for (int i = 0; i < 4; ++i)
#pragma unroll
    for (int j = 0; j < 4; ++j) acc[i][j] = (floatx4){0.f, 0.f, 0.f, 0.f};

  const int fm = lane & 15;      // A: m, B: n
  const int fq = lane >> 4;      // k-chunk: k = fq*32 + byte
  const int SC1 = 0x7F7F7F7F;    // e8m0 scale = 1.0 in every byte

  for (int k0 = 0; k0 < 4096; k0 += 128) {
#pragma unroll
    for (int q = 0; q < 4; ++q) GLOAD_LDS16(Ag + k0 + q * 32, AsB[q]);
#pragma unroll
    for (int q = 0; q < 4; ++q) GLOAD_LDS16(Bg + k0 + q * 32, BsB[q]);
    __syncthreads();

    i32x8 af[4], bfr[4];
#pragma unroll
    for (int i = 0; i < 4; ++i)
      af[i] = *reinterpret_cast<const i32x8*>(&As[fq][wr * 64 + i * 16 + fm][0]);
#pragma unroll
    for (int j = 0; j < 4; ++j)
      bfr[j] = *reinterpret_cast<const i32x8*>(&Bs[fq][wc * 64 + j * 16 + fm][0]);
#pragma unroll
    for (int i = 0; i < 4; ++i)
#pragma unroll
      for (int j = 0; j < 4; ++j)
        acc[i][j] = __builtin_amdgcn_mfma_scale_f32_16x16x128_f8f6f4(
            af[i], bfr[j], acc[i][j], 0, 0, 0, SC1, 0, SC1);
    __syncthreads();
  }

  // C/D mapping (shape-determined): col = lane&15, row = (lane>>4)*4 + reg
  float* Cz = C + (size_t)blockIdx.z * M_DIM * N_NODES;
  const int cr = (lane >> 4) * 4;
  const int cc = lane & 15;
#pragma unroll
  for (int i = 0; i < 4; ++i)
#pragma unroll
    for (int j = 0; j < 4; ++j) {
      float* Cp = Cz + (size_t)(m0 + wr * 64 + i * 16 + cr) * N_NODES
                     + (n0 + wc * 64 + j * 16 + cc);
#pragma unroll
      for (int r = 0; r < 4; ++r) Cp[(size_t)r * N_NODES] = acc[i][j][r];
    }
}

// ---------------- kernel 3: epilogue: sum K-partials, /4096, bias, W_lin, PReLU,
// concat h, W_read.  thread owns 4 n x 16 d'.
__global__ __launch_bounds__(256) void k_epilogue(
    const float* __restrict__ C0, const float* __restrict__ C1,
    const float* __restrict__ h,
    const float* __restrict__ bmlp, const float* __restrict__ Wlin,
    const float* __restrict__ blin, const float* __restrict__ Wread,
    const float* __restrict__ bread, const float* __restrict__ pa,
    float* __restrict__ out0, float* __restrict__ out1) {
  __shared__ __align__(16) float sW[DM * 132];
  __shared__ float sbm[DM], sbl[DM], sWr[128];
  __shared__ float psum[3 * 256];
  for (uint32_t t = threadIdx.x; t < DM * 128; t += 256) {
    uint32_t d = t >> 7, c = t & 127u;
    sW[d * 132 + c] = Wlin[t];
  }
  if (threadIdx.x < DM) { sbm[threadIdx.x] = bmlp[threadIdx.x]; sbl[threadIdx.x] = blin[threadIdx.x]; }
  if (threadIdx.x < 128) sWr[threadIdx.x] = Wread[threadIdx.x];
  __syncthreads();

  uint32_t bi = blockIdx.x;                  // 32 b x 16 n0 = 512 blocks
  uint32_t n0 = (bi & 15u) * 256u;
  uint32_t b  = bi >> 4;
  const uint32_t tv = threadIdx.x & 63u;
  const uint32_t td = threadIdx.x >> 6;
  const uint32_t n  = n0 + tv * 4u;
  const float KS = 1.0f / 4096.0f;           // undo adj*4096 scaling

  float acc[16][4];
#pragma unroll
  for (int d = 0; d < 16; ++d) {
    float bl = sbl[td * 16 + d];
#pragma unroll
    for (int k = 0; k < 4; ++k) acc[d][k] = bl;
  }

  for (int c0 = 0; c0 < 64; c0 += 4) {       // channels 0..63 = graph-conv out
    float4 in4[4];
#pragma unroll
    for (int j = 0; j < 4; ++j) {
      size_t off = ((size_t)b * DM + (c0 + j)) * N_NODES + n;
      float4 v0 = *reinterpret_cast<const float4*>(C0 + off);
      float4 v1 = *reinterpret_cast<const float4*>(C1 + off);
      float bm = sbm[c0 + j];
      float4 v;
      v.x = (v0.x + v1.x) * KS + bm; v.y = (v0.y + v1.y) * KS + bm;
      v.z = (v0.z + v1.z) * KS + bm; v.w = (v0.w + v1.w) * KS + bm;
      in4[j] = v;
    }
#pragma unroll
    for (int d = 0; d < 16; ++d) {
      const float4 w4 = *reinterpret_cast<const float4*>(&sW[(td * 16 + d) * 132 + c0]);
      acc[d][0] += w4.x * in4[0].x + w4.y * in4[1].x + w4.z * in4[2].x + w4.w * in4[3].x;
      acc[d][1] += w4.x * in4[0].y + w4.y * in4[1].y + w4.z * in4[2].y + w4.w * in4[3].y;
      acc[d][2] += w4.x * in4[0].z + w4.y * in4[1].z + w4.z * in4[2].z + w4.w * in4[3].z;
      acc[d][3] += w4.x * in4[0].w + w4.y * in4[1].w + w4.z * in4[2].w + w4.w * in4[3].w;
    }
  }
  for (int c0 = 0; c0 < 64; c0 += 4) {       // channels 64..127 = h
    float4 in4[4];
#pragma unroll
    for (int j = 0; j < 4; ++j)
      in4[j] = *reinterpret_cast<const float4*>(h + ((size_t)b * DM + (c0 + j)) * N_NODES + n);
#pragma unroll
    for (int d = 0; d < 16; ++d) {
      const float4 w4 = *reinterpret_cast<const float4*>(&sW[(td * 16 + d) * 132 + 64 + c0]);
      acc[d][0] += w4.x * in4[0].x + w4.y * in4[1].x + w4.z * in4[2].x + w4.w * in4[3].x;
      acc[d][1] += w4.x * in4[0].y + w4.y * in4[1].y + w4.z * in4[2].y + w4.w * in4[3].y;
      acc[d][2] += w4.x * in4[0].z + w4.y * in4[1].z + w4.z * in4[2].z + w4.w * in4[3].z;
      acc[d][3] += w4.x * in4[0].w + w4.y * in4[1].w + w4.z * in4[2].w + w4.w * in4[3].w;
    }
  }

  const float a = pa[0];
  float r[4] = {0.f, 0.f, 0.f, 0.f};
  float* o1b = out1 + (size_t)b * 128 * N_NODES + n;
#pragma unroll
  for (int d = 0; d < 16; ++d) {
    float4 o2;
    o2.x = acc[d][0] >= 0.f ? acc[d][0] : a * acc[d][0];
    o2.y = acc[d][1] >= 0.f ? acc[d][1] : a * acc[d][1];
    o2.z = acc[d][2] >= 0.f ? acc[d][2] : a * acc[d][2];
    o2.w = acc[d][3] >= 0.f ? acc[d][3] : a * acc[d][3];
    *reinterpret_cast<float4*>(o1b + (size_t)(td * 16 + d) * N_NODES) = o2;
    float wr = sWr[td * 16 + d];
    r[0] += wr * o2.x; r[1] += wr * o2.y; r[2] += wr * o2.z; r[3] += wr * o2.w;
  }
#pragma unroll
  for (int d = 0; d < 16; ++d) {
    float4 hv = *reinterpret_cast<const float4*>(h + ((size_t)b * DM + td * 16 + d) * N_NODES + n);
    *reinterpret_cast<float4*>(o1b + (size_t)(64 + td * 16 + d) * N_NODES) = hv;
    float wr = sWr[64 + td * 16 + d];
    r[0] += wr * hv.x; r[1] += wr * hv.y; r[2] += wr * hv.z; r[3] += wr * hv.w;
  }
  if (td > 0) {
#pragma unroll
    for (int k = 0; k < 4; ++k) psum[(td - 1) * 256 + tv * 4 + k] = r[k];
  }
  __syncthreads();
  if (td == 0) {
    float br = bread[0];
#pragma unroll
    for (int k = 0; k < 4; ++k)
      r[k] += br + psum[tv * 4 + k] + psum[256 + tv * 4 + k] + psum[512 + tv * 4 + k];
    float4 o0; o0.x = r[0]; o0.y = r[1]; o0.z = r[2]; o0.w = r[3];
    *reinterpret_cast<float4*>(out0 + (size_t)b * N_NODES + n) = o0;
  }
}

extern "C" void kernel_launch(void* const* d_in, const int* in_sizes, int n_in,
                              void* d_out, int out_size, void* d_ws, size_t ws_size,
                              hipStream_t stream) {
  const float* x     = (const float*)d_in[0];
  const float* h     = (const float*)d_in[1];
  const float* adj   = (const float*)d_in[2];
  const float* Wmlp  = (const float*)d_in[3];
  const float* bmlp  = (const float*)d_in[4];
  const float* Wlin  = (const float*)d_in[5];
  const float* blin  = (const float*)d_in[6];
  const float* Wread = (const float*)d_in[7];
  const float* bread = (const float*)d_in[8];
  const float* pa    = (const float*)d_in[9];

  char* ws = (char*)d_ws;
  u8*    Abuf  = (u8*)ws;                        // 2048*8192      = 16 MiB
  u8*    BTbuf = (u8*)(ws + (16ull << 20));      // 4096*8192      = 32 MiB
  float* C0    = (float*)(ws + (48ull << 20));   // 2048*4096*4    = 32 MiB
  float* C1    = (float*)(ws + (80ull << 20));   // 2048*4096*4    = 32 MiB
  float* out0 = (float*)d_out;                   // [32,1,4096]
  float* out1 = out0 + 131072;                   // [32,128,4096]

  hipLaunchKernelGGL(k_prep,     dim3(17408),     dim3(256), 0, stream,
                     adj, BTbuf, x, h, Wmlp, Abuf);
  hipLaunchKernelGGL(k_gemm,     dim3(32, 16, 2), dim3(256), 0, stream, Abuf, BTbuf, C0);
  hipLaunchKernelGGL(k_epilogue, dim3(512),       dim3(256), 0, stream, C0, C1, h, bmlp,
                     Wlin, blin, Wread, bread, pa, out0, out1);
}